// Round 9
// baseline (454.802 us; speedup 1.0000x reference)
//
#include <hip/hip_runtime.h>
#include <math.h>

#define N_NODES 50000
#define N_EDGES 400000
#define HD 32
#define N_ET 8
#define CAP 64   // ELL capacity; Poisson(8) max degree ~30, P(>=64) ~ 1e-40

__device__ inline void fma4(float4& a, float s, const float4 w) {
    a.x = fmaf(s, w.x, a.x);
    a.y = fmaf(s, w.y, a.y);
    a.z = fmaf(s, w.z, a.z);
    a.w = fmaf(s, w.w, a.w);
}
__device__ inline void add4(float4& a, const float4 v) {
    a.x += v.x; a.y += v.y; a.z += v.z; a.w += v.w;
}

// Build ELL adjacency keyed by dst: payload[d][k] = pid*N_NODES + src
__global__ __launch_bounds__(256) void k_count(
    const int* __restrict__ src, const int* __restrict__ dst,
    const int* __restrict__ pid, int* __restrict__ deg,
    int* __restrict__ payload)
{
    int e = blockIdx.x * blockDim.x + threadIdx.x;
    if (e >= N_EDGES) return;
    int d = dst[e];
    int pos = atomicAdd(&deg[d], 1);
    if (pos < CAP) payload[d * CAP + pos] = pid[e] * N_NODES + src[e];
}

// Transform: Y[t][n] = x[n] @ W_t.  One edge-type per block (blockIdx.y) so the
// weight pointer is wave-uniform -> s_load; one node per thread.
__global__ __launch_bounds__(256) void k_transform(
    const float* __restrict__ xin, const float* __restrict__ param,
    float* __restrict__ Y)
{
    int n = blockIdx.x * blockDim.x + threadIdx.x;
    if (n >= N_NODES) return;
    const int t = blockIdx.y;
    const size_t base = (size_t)n * HD;
    const float* W = param + t * (HD * HD);

    float x[HD];
    #pragma unroll
    for (int q = 0; q < 8; ++q) {
        float4 v = *(const float4*)(xin + base + q * 4);
        x[q * 4 + 0] = v.x; x[q * 4 + 1] = v.y;
        x[q * 4 + 2] = v.z; x[q * 4 + 3] = v.w;
    }

    float4 acc[8];
    #pragma unroll
    for (int q = 0; q < 8; ++q) acc[q] = make_float4(0.f, 0.f, 0.f, 0.f);
    #pragma unroll
    for (int i = 0; i < HD; ++i) {
        float xi = x[i];
        #pragma unroll
        for (int q = 0; q < 8; ++q)
            fma4(acc[q], xi, *(const float4*)(W + i * HD + q * 4));
    }
    float* yo = Y + (size_t)t * N_NODES * HD + base;
    #pragma unroll
    for (int q = 0; q < 8; ++q) *(float4*)(yo + q * 4) = acc[q];
}

// Gather + combine: xout[n] = (xin[n] + sum_{e in in(n)} Y[pid_e][src_e]) * 0.5
// 8 lanes per node; lane sl owns a 16B slice. 4 edges in flight (MLP=4).
__global__ __launch_bounds__(256) void k_gather(
    const int* __restrict__ deg, const int* __restrict__ payload,
    const float* __restrict__ Y, const float* __restrict__ xin,
    float* __restrict__ xout)
{
    int tid = blockIdx.x * blockDim.x + threadIdx.x;
    int node = tid >> 3, sl = tid & 7;
    if (node >= N_NODES) return;
    int d = deg[node];
    if (d > CAP) d = CAP;
    const int* pl = payload + node * CAP;

    float4 a0 = make_float4(0.f,0.f,0.f,0.f), a1 = a0, a2 = a0, a3 = a0;
    int k = 0;
    for (; k + 4 <= d; k += 4) {
        int4 c = *(const int4*)(pl + k);              // 16B aligned (k%4==0)
        float4 v0 = *(const float4*)(Y + (size_t)c.x * HD + sl * 4);
        float4 v1 = *(const float4*)(Y + (size_t)c.y * HD + sl * 4);
        float4 v2 = *(const float4*)(Y + (size_t)c.z * HD + sl * 4);
        float4 v3 = *(const float4*)(Y + (size_t)c.w * HD + sl * 4);
        add4(a0, v0); add4(a1, v1); add4(a2, v2); add4(a3, v3);
    }
    for (; k < d; ++k) {
        int c = pl[k];
        add4(a0, *(const float4*)(Y + (size_t)c * HD + sl * 4));
    }
    add4(a0, a1); add4(a2, a3); add4(a0, a2);

    const size_t off = (size_t)node * HD + sl * 4;
    float4 x = *(const float4*)(xin + off);
    x.x = (x.x + a0.x) * 0.5f;
    x.y = (x.y + a0.y) * 0.5f;
    x.z = (x.z + a0.z) * 0.5f;
    x.w = (x.w + a0.w) * 0.5f;
    *(float4*)(xout + off) = x;
}

// Layer-3 gather fused with: L2-normalize ; MLP 32->64 tanh ->64 tanh ->1 ; sigmoid.
// __launch_bounds__(256,4): force VGPR<=128 to cross the 128-VGPR occupancy
// cliff (R8: 148 VGPR -> 2 waves/SIMD, 9% occupancy, latency-bound).
// Gather uses 2 accumulators (loads still 4-deep) to hand the allocator slack.
__global__ __launch_bounds__(256, 4) void k_gather_final(
    const int* __restrict__ deg, const int* __restrict__ payload,
    const float* __restrict__ Y, const float* __restrict__ xin,
    const float* __restrict__ w1, const float* __restrict__ b1,
    const float* __restrict__ w2, const float* __restrict__ b2,
    const float* __restrict__ w3, const float* __restrict__ b3,
    float* __restrict__ out)
{
    int tid = blockIdx.x * blockDim.x + threadIdx.x;
    int node = tid >> 3, q = tid & 7;
    if (node >= N_NODES) return;                 // whole 8-lane group exits together
    int d = deg[node];
    if (d > CAP) d = CAP;
    const int* pl = payload + node * CAP;

    // gather own 16B slice (4 loads in flight, 2 accumulators)
    float4 a0 = make_float4(0.f,0.f,0.f,0.f), a1 = a0;
    int k = 0;
    for (; k + 4 <= d; k += 4) {
        int4 c = *(const int4*)(pl + k);
        float4 v0 = *(const float4*)(Y + (size_t)c.x * HD + q * 4);
        float4 v1 = *(const float4*)(Y + (size_t)c.y * HD + q * 4);
        float4 v2 = *(const float4*)(Y + (size_t)c.z * HD + q * 4);
        float4 v3 = *(const float4*)(Y + (size_t)c.w * HD + q * 4);
        add4(a0, v0); add4(a1, v1); add4(a0, v2); add4(a1, v3);
    }
    for (; k < d; ++k) {
        int c = pl[k];
        add4(a0, *(const float4*)(Y + (size_t)c * HD + q * 4));
    }
    add4(a0, a1);

    float4 xo = *(const float4*)(xin + (size_t)node * HD + q * 4);
    xo.x = (xo.x + a0.x) * 0.5f;
    xo.y = (xo.y + a0.y) * 0.5f;
    xo.z = (xo.z + a0.z) * 0.5f;
    xo.w = (xo.w + a0.w) * 0.5f;

    // L2 norm across the 8 lanes
    float ss = xo.x * xo.x + xo.y * xo.y + xo.z * xo.z + xo.w * xo.w;
    ss += __shfl_xor(ss, 1, 8);
    ss += __shfl_xor(ss, 2, 8);
    ss += __shfl_xor(ss, 4, 8);
    float rn = 1.0f / fmaxf(sqrtf(ss), 1e-12f);
    xo.x *= rn; xo.y *= rn; xo.z *= rn; xo.w *= rn;

    // layer 1: h = x @ w1 + b1, cols [8q, 8q+8)
    float4 h0 = *(const float4*)(b1 + q * 8);
    float4 h1 = *(const float4*)(b1 + q * 8 + 4);
    for (int s = 0; s < 8; ++s) {                // rolled: bounded live set
        float m0 = __shfl(xo.x, s, 8);
        float m1 = __shfl(xo.y, s, 8);
        float m2 = __shfl(xo.z, s, 8);
        float m3 = __shfl(xo.w, s, 8);
        const float* wr = w1 + (s * 4) * 64 + q * 8;
        fma4(h0, m0, *(const float4*)(wr));
        fma4(h1, m0, *(const float4*)(wr + 4));
        fma4(h0, m1, *(const float4*)(wr + 64));
        fma4(h1, m1, *(const float4*)(wr + 68));
        fma4(h0, m2, *(const float4*)(wr + 128));
        fma4(h1, m2, *(const float4*)(wr + 132));
        fma4(h0, m3, *(const float4*)(wr + 192));
        fma4(h1, m3, *(const float4*)(wr + 196));
    }
    float t1[8];
    t1[0] = tanhf(h0.x); t1[1] = tanhf(h0.y); t1[2] = tanhf(h0.z); t1[3] = tanhf(h0.w);
    t1[4] = tanhf(h1.x); t1[5] = tanhf(h1.y); t1[6] = tanhf(h1.z); t1[7] = tanhf(h1.w);

    // layer 2: h2 = t1 @ w2 + b2, cols [8q, 8q+8)
    float4 g0 = *(const float4*)(b2 + q * 8);
    float4 g1 = *(const float4*)(b2 + q * 8 + 4);
    for (int s = 0; s < 8; ++s) {                // rolled over source lane
        const float* wr = w2 + (s * 8) * 64 + q * 8;
        #pragma unroll
        for (int c = 0; c < 8; ++c) {
            float m = __shfl(t1[c], s, 8);
            fma4(g0, m, *(const float4*)(wr + c * 64));
            fma4(g1, m, *(const float4*)(wr + c * 64 + 4));
        }
    }

    // layer 3: partial dot over own 8 cols, reduce across the 8 lanes
    float4 wa = *(const float4*)(w3 + q * 8);
    float4 wb = *(const float4*)(w3 + q * 8 + 4);
    float p = 0.f;
    p = fmaf(tanhf(g0.x), wa.x, p);
    p = fmaf(tanhf(g0.y), wa.y, p);
    p = fmaf(tanhf(g0.z), wa.z, p);
    p = fmaf(tanhf(g0.w), wa.w, p);
    p = fmaf(tanhf(g1.x), wb.x, p);
    p = fmaf(tanhf(g1.y), wb.y, p);
    p = fmaf(tanhf(g1.z), wb.z, p);
    p = fmaf(tanhf(g1.w), wb.w, p);
    p += __shfl_xor(p, 1, 8);
    p += __shfl_xor(p, 2, 8);
    p += __shfl_xor(p, 4, 8);
    if (q == 0) out[node] = 1.0f / (1.0f + expf(-(p + b3[0])));
}

extern "C" void kernel_launch(void* const* d_in, const int* in_sizes, int n_in,
                              void* d_out, int out_size, void* d_ws, size_t ws_size,
                              hipStream_t stream) {
    const float* feature = (const float*)d_in[0];
    const float* param   = (const float*)d_in[1];
    const float* w1      = (const float*)d_in[2];
    const float* b1      = (const float*)d_in[3];
    const float* w2      = (const float*)d_in[4];
    const float* b2      = (const float*)d_in[5];
    const float* w3      = (const float*)d_in[6];
    const float* b3      = (const float*)d_in[7];
    const int*   src     = (const int*)d_in[8];
    const int*   dst     = (const int*)d_in[9];
    const int*   pid     = (const int*)d_in[10];
    float* out = (float*)d_out;

    const size_t Y_BYTES   = (size_t)N_ET * N_NODES * HD * sizeof(float);   // 51.2 MB
    const size_t NH_BYTES  = (size_t)N_NODES * HD * sizeof(float);          // 6.4 MB
    const size_t DEG_BYTES = (size_t)N_NODES * sizeof(int);                 // 0.2 MB
    char* p = (char*)d_ws;
    float* Y       = (float*)p;            p += Y_BYTES;
    float* cur     = (float*)p;            p += NH_BYTES;
    int*   deg     = (int*)p;              p += DEG_BYTES;
    int*   payload = (int*)p;              // 50K * 64 * 4B = 12.8 MB

    const int TB = 256;
    const int gT = (N_NODES + TB - 1) / TB;          // 196
    const int gE = (N_EDGES + TB - 1) / TB;
    const int gG = (N_NODES * 8 + TB - 1) / TB;      // 1563
    dim3 gridT(gT, N_ET);                            // 1568 blocks, t uniform per block

    // Build dst-keyed ELL adjacency (int atomics only, once per launch)
    hipMemsetAsync(deg, 0, DEG_BYTES, stream);
    k_count<<<gE, TB, 0, stream>>>(src, dst, pid, deg, payload);

    // layer 1
    k_transform<<<gridT, TB, 0, stream>>>(feature, param, Y);
    k_gather<<<gG, TB, 0, stream>>>(deg, payload, Y, feature, cur);
    // layer 2
    k_transform<<<gridT, TB, 0, stream>>>(cur, param, Y);
    k_gather<<<gG, TB, 0, stream>>>(deg, payload, Y, cur, cur);
    // layer 3: gather fused with normalize + MLP + sigmoid
    k_transform<<<gridT, TB, 0, stream>>>(cur, param, Y);
    k_gather_final<<<gG, TB, 0, stream>>>(deg, payload, Y, cur,
                                          w1, b1, w2, b2, w3, b3, out);
}

// Round 10
// 400.006 us; speedup vs baseline: 1.1370x; 1.1370x over previous
//
#include <hip/hip_runtime.h>
#include <math.h>

#define N_NODES 50000
#define N_EDGES 400000
#define HD 32
#define N_ET 8
#define CAP_T 16  // per-(node,type) ELL capacity; edges/bin ~Poisson(1), P(>=16)~1e-13

__device__ inline void fma4(float4& a, float s, const float4 w) {
    a.x = fmaf(s, w.x, a.x);
    a.y = fmaf(s, w.y, a.y);
    a.z = fmaf(s, w.z, a.z);
    a.w = fmaf(s, w.w, a.w);
}
__device__ inline void add4(float4& a, const float4 v) {
    a.x += v.x; a.y += v.y; a.z += v.z; a.w += v.w;
}

// Bin edges by (dst, type): cnt[d*8+t], payload[(d*8+t)*CAP_T + k] = src
__global__ __launch_bounds__(256) void k_count(
    const int* __restrict__ src, const int* __restrict__ dst,
    const int* __restrict__ pid, int* __restrict__ cnt,
    int* __restrict__ payload)
{
    int e = blockIdx.x * blockDim.x + threadIdx.x;
    if (e >= N_EDGES) return;
    int bin = dst[e] * N_ET + pid[e];
    int pos = atomicAdd(&cnt[bin], 1);
    if (pos < CAP_T) payload[(size_t)bin * CAP_T + pos] = src[e];
}

// Per-node layer step, 8 lanes/node, lane q owns elems [4q,4q+4):
//   for each type t: s = sum of x[src] over bin(node,t); out += s @ W_t
// (matvec via width-8 shuffle broadcast of s; weight loads shared across the
// wave's 8 node-groups -> L1 broadcast). No Y intermediate at all.
__device__ __forceinline__ float4 layer_combine(
    int node, int q, const int* __restrict__ cnt, const int* __restrict__ payload,
    const float* __restrict__ x, const float* __restrict__ param)
{
    float4 out = make_float4(0.f, 0.f, 0.f, 0.f);
    for (int t = 0; t < N_ET; ++t) {             // rolled: W offset uniform, regs bounded
        int c = cnt[node * N_ET + t];
        if (c > CAP_T) c = CAP_T;
        if (c == 0) continue;                    // group-uniform branch (8-lane groups)
        const int* pl = payload + ((size_t)node * N_ET + t) * CAP_T;
        float4 s = make_float4(0.f, 0.f, 0.f, 0.f);
        int k = 0;
        for (; k + 4 <= c; k += 4) {
            int4 e4 = *(const int4*)(pl + k);    // 16B aligned
            float4 v0 = *(const float4*)(x + (size_t)e4.x * HD + q * 4);
            float4 v1 = *(const float4*)(x + (size_t)e4.y * HD + q * 4);
            float4 v2 = *(const float4*)(x + (size_t)e4.z * HD + q * 4);
            float4 v3 = *(const float4*)(x + (size_t)e4.w * HD + q * 4);
            add4(s, v0); add4(s, v1); add4(s, v2); add4(s, v3);
        }
        for (; k < c; ++k)
            add4(s, *(const float4*)(x + (size_t)pl[k] * HD + q * 4));

        const float* W = param + t * (HD * HD);
        #pragma unroll
        for (int sl = 0; sl < 8; ++sl) {
            float m0 = __shfl(s.x, sl, 8);
            float m1 = __shfl(s.y, sl, 8);
            float m2 = __shfl(s.z, sl, 8);
            float m3 = __shfl(s.w, sl, 8);
            const float* wr = W + (sl * 4) * HD + q * 4;
            fma4(out, m0, *(const float4*)(wr));
            fma4(out, m1, *(const float4*)(wr + HD));
            fma4(out, m2, *(const float4*)(wr + 2 * HD));
            fma4(out, m3, *(const float4*)(wr + 3 * HD));
        }
    }
    return out;
}

// One GNN layer: xout = (xin + agg) * 0.5   (xin != xout: gather reads xin)
__global__ __launch_bounds__(256) void k_layer(
    const int* __restrict__ cnt, const int* __restrict__ payload,
    const float* __restrict__ xin, const float* __restrict__ param,
    float* __restrict__ xout)
{
    int tid = blockIdx.x * blockDim.x + threadIdx.x;
    int node = tid >> 3, q = tid & 7;
    if (node >= N_NODES) return;
    float4 agg = layer_combine(node, q, cnt, payload, xin, param);
    const size_t off = (size_t)node * HD + q * 4;
    float4 xo = *(const float4*)(xin + off);
    xo.x = (xo.x + agg.x) * 0.5f;
    xo.y = (xo.y + agg.y) * 0.5f;
    xo.z = (xo.z + agg.z) * 0.5f;
    xo.w = (xo.w + agg.w) * 0.5f;
    *(float4*)(xout + off) = xo;
}

// Layer 3 fused with: L2-normalize ; MLP 32->64 tanh ->64 tanh ->1 ; sigmoid.
// Same 8-lane layout as R8 (lane q owns x[4q..4q+4), hidden cols [8q,8q+8)).
// Natural register allocation (R9 lesson: forcing waves/EU caused 366MB spill).
__global__ __launch_bounds__(256) void k_layer_final(
    const int* __restrict__ cnt, const int* __restrict__ payload,
    const float* __restrict__ xin, const float* __restrict__ param,
    const float* __restrict__ w1, const float* __restrict__ b1,
    const float* __restrict__ w2, const float* __restrict__ b2,
    const float* __restrict__ w3, const float* __restrict__ b3,
    float* __restrict__ out)
{
    int tid = blockIdx.x * blockDim.x + threadIdx.x;
    int node = tid >> 3, q = tid & 7;
    if (node >= N_NODES) return;
    float4 agg = layer_combine(node, q, cnt, payload, xin, param);
    float4 xo = *(const float4*)(xin + (size_t)node * HD + q * 4);
    xo.x = (xo.x + agg.x) * 0.5f;
    xo.y = (xo.y + agg.y) * 0.5f;
    xo.z = (xo.z + agg.z) * 0.5f;
    xo.w = (xo.w + agg.w) * 0.5f;

    // L2 norm across the 8 lanes
    float ss = xo.x * xo.x + xo.y * xo.y + xo.z * xo.z + xo.w * xo.w;
    ss += __shfl_xor(ss, 1, 8);
    ss += __shfl_xor(ss, 2, 8);
    ss += __shfl_xor(ss, 4, 8);
    float rn = 1.0f / fmaxf(sqrtf(ss), 1e-12f);
    xo.x *= rn; xo.y *= rn; xo.z *= rn; xo.w *= rn;

    // layer 1: h = x @ w1 + b1, cols [8q, 8q+8)
    float4 h0 = *(const float4*)(b1 + q * 8);
    float4 h1 = *(const float4*)(b1 + q * 8 + 4);
    for (int s = 0; s < 8; ++s) {                // rolled: bounded live set
        float m0 = __shfl(xo.x, s, 8);
        float m1 = __shfl(xo.y, s, 8);
        float m2 = __shfl(xo.z, s, 8);
        float m3 = __shfl(xo.w, s, 8);
        const float* wr = w1 + (s * 4) * 64 + q * 8;
        fma4(h0, m0, *(const float4*)(wr));
        fma4(h1, m0, *(const float4*)(wr + 4));
        fma4(h0, m1, *(const float4*)(wr + 64));
        fma4(h1, m1, *(const float4*)(wr + 68));
        fma4(h0, m2, *(const float4*)(wr + 128));
        fma4(h1, m2, *(const float4*)(wr + 132));
        fma4(h0, m3, *(const float4*)(wr + 192));
        fma4(h1, m3, *(const float4*)(wr + 196));
    }
    float t1[8];
    t1[0] = tanhf(h0.x); t1[1] = tanhf(h0.y); t1[2] = tanhf(h0.z); t1[3] = tanhf(h0.w);
    t1[4] = tanhf(h1.x); t1[5] = tanhf(h1.y); t1[6] = tanhf(h1.z); t1[7] = tanhf(h1.w);

    // layer 2: h2 = t1 @ w2 + b2, cols [8q, 8q+8)
    float4 g0 = *(const float4*)(b2 + q * 8);
    float4 g1 = *(const float4*)(b2 + q * 8 + 4);
    for (int s = 0; s < 8; ++s) {                // rolled over source lane
        const float* wr = w2 + (s * 8) * 64 + q * 8;
        #pragma unroll
        for (int c = 0; c < 8; ++c) {
            float m = __shfl(t1[c], s, 8);
            fma4(g0, m, *(const float4*)(wr + c * 64));
            fma4(g1, m, *(const float4*)(wr + c * 64 + 4));
        }
    }

    // layer 3: partial dot over own 8 cols, reduce across the 8 lanes
    float4 wa = *(const float4*)(w3 + q * 8);
    float4 wb = *(const float4*)(w3 + q * 8 + 4);
    float p = 0.f;
    p = fmaf(tanhf(g0.x), wa.x, p);
    p = fmaf(tanhf(g0.y), wa.y, p);
    p = fmaf(tanhf(g0.z), wa.z, p);
    p = fmaf(tanhf(g0.w), wa.w, p);
    p = fmaf(tanhf(g1.x), wb.x, p);
    p = fmaf(tanhf(g1.y), wb.y, p);
    p = fmaf(tanhf(g1.z), wb.z, p);
    p = fmaf(tanhf(g1.w), wb.w, p);
    p += __shfl_xor(p, 1, 8);
    p += __shfl_xor(p, 2, 8);
    p += __shfl_xor(p, 4, 8);
    if (q == 0) out[node] = 1.0f / (1.0f + expf(-(p + b3[0])));
}

extern "C" void kernel_launch(void* const* d_in, const int* in_sizes, int n_in,
                              void* d_out, int out_size, void* d_ws, size_t ws_size,
                              hipStream_t stream) {
    const float* feature = (const float*)d_in[0];
    const float* param   = (const float*)d_in[1];
    const float* w1      = (const float*)d_in[2];
    const float* b1      = (const float*)d_in[3];
    const float* w2      = (const float*)d_in[4];
    const float* b2      = (const float*)d_in[5];
    const float* w3      = (const float*)d_in[6];
    const float* b3      = (const float*)d_in[7];
    const int*   src     = (const int*)d_in[8];
    const int*   dst     = (const int*)d_in[9];
    const int*   pid     = (const int*)d_in[10];
    float* out = (float*)d_out;

    const size_t CNT_BYTES = (size_t)N_NODES * N_ET * sizeof(int);            // 1.6 MB
    const size_t PAY_BYTES = (size_t)N_NODES * N_ET * CAP_T * sizeof(int);    // 25.6 MB
    const size_t NH_BYTES  = (size_t)N_NODES * HD * sizeof(float);            // 6.4 MB
    char* p = (char*)d_ws;
    int*   cnt     = (int*)p;              p += CNT_BYTES;
    int*   payload = (int*)p;              p += PAY_BYTES;
    float* c0      = (float*)p;            p += NH_BYTES;
    float* c1      = (float*)p;            // double-buffer (in-place would race)

    const int TB = 256;
    const int gE = (N_EDGES + TB - 1) / TB;
    const int gL = (N_NODES * 8 + TB - 1) / TB;      // 1563

    // Bin edges by (dst, type)
    hipMemsetAsync(cnt, 0, CNT_BYTES, stream);
    k_count<<<gE, TB, 0, stream>>>(src, dst, pid, cnt, payload);

    // 3 GNN layers (no Y intermediate; typed sums + in-register matvecs)
    k_layer<<<gL, TB, 0, stream>>>(cnt, payload, feature, param, c0);
    k_layer<<<gL, TB, 0, stream>>>(cnt, payload, c0, param, c1);
    k_layer_final<<<gL, TB, 0, stream>>>(cnt, payload, c1, param,
                                         w1, b1, w2, b2, w3, b3, out);
}

// Round 11
// 277.422 us; speedup vs baseline: 1.6394x; 1.4419x over previous
//
#include <hip/hip_runtime.h>
#include <math.h>

#define N_NODES 50000
#define N_EDGES 400000
#define HD 32
#define N_ET 8
#define CAP 64   // ELL capacity; Poisson(8) max degree ~30, P(>=64) ~ 1e-40

__device__ inline void fma4(float4& a, float s, const float4 w) {
    a.x = fmaf(s, w.x, a.x);
    a.y = fmaf(s, w.y, a.y);
    a.z = fmaf(s, w.z, a.z);
    a.w = fmaf(s, w.w, a.w);
}
__device__ inline void add4(float4& a, const float4 v) {
    a.x += v.x; a.y += v.y; a.z += v.z; a.w += v.w;
}
// predicated accumulate: a += v * m  (m is 0 or 1)
__device__ inline void fmam4(float4& a, const float4 v, float m) {
    a.x = fmaf(m, v.x, a.x);
    a.y = fmaf(m, v.y, a.y);
    a.z = fmaf(m, v.z, a.z);
    a.w = fmaf(m, v.w, a.w);
}

// Build ELL adjacency keyed by dst: payload[d][k] = pid*N_NODES + src
__global__ __launch_bounds__(256) void k_count(
    const int* __restrict__ src, const int* __restrict__ dst,
    const int* __restrict__ pid, int* __restrict__ deg,
    int* __restrict__ payload)
{
    int e = blockIdx.x * blockDim.x + threadIdx.x;
    if (e >= N_EDGES) return;
    int d = dst[e];
    int pos = atomicAdd(&deg[d], 1);
    if (pos < CAP) payload[d * CAP + pos] = pid[e] * N_NODES + src[e];
}

// Transform: Y[t][n] = x[n] @ W_t.  One edge-type per block (blockIdx.y).
// W_t staged in LDS (4 KB); inner loop reads W via uniform-address ds_read
// (hardware broadcast) instead of inline s_loads, which serialized pre-R11
// (R2 counters: VALUBusy ~10%; 1024 FMAs/thread stalled on scalar cache).
__global__ __launch_bounds__(256) void k_transform(
    const float* __restrict__ xin, const float* __restrict__ param,
    float* __restrict__ Y)
{
    __shared__ float Ws[HD * HD];                 // 4 KB
    const int t = blockIdx.y;
    // cooperative load: 256 threads x one float4 = 1024 floats
    ((float4*)Ws)[threadIdx.x] =
        ((const float4*)(param + t * HD * HD))[threadIdx.x];
    __syncthreads();

    int n = blockIdx.x * blockDim.x + threadIdx.x;
    if (n >= N_NODES) return;
    const size_t base = (size_t)n * HD;

    float x[HD];
    #pragma unroll
    for (int q = 0; q < 8; ++q) {
        float4 v = *(const float4*)(xin + base + q * 4);
        x[q * 4 + 0] = v.x; x[q * 4 + 1] = v.y;
        x[q * 4 + 2] = v.z; x[q * 4 + 3] = v.w;
    }

    float4 acc[8];
    #pragma unroll
    for (int q = 0; q < 8; ++q) acc[q] = make_float4(0.f, 0.f, 0.f, 0.f);
    #pragma unroll
    for (int i = 0; i < HD; ++i) {
        float xi = x[i];
        #pragma unroll
        for (int q = 0; q < 8; ++q)
            fma4(acc[q], xi, *(const float4*)(Ws + i * HD + q * 4));
    }
    float* yo = Y + (size_t)t * N_NODES * HD + base;
    #pragma unroll
    for (int q = 0; q < 8; ++q) *(float4*)(yo + q * 4) = acc[q];
}

// Gather + combine: xout[n] = (xin[n] + sum_{e in in(n)} Y[pid_e][src_e]) * 0.5
// 8 lanes per node; lane sl owns a 16B slice. 8 loads in flight per round;
// tail handled by clamped-index predication (no serial tail loop).
__global__ __launch_bounds__(256) void k_gather(
    const int* __restrict__ deg, const int* __restrict__ payload,
    const float* __restrict__ Y, const float* __restrict__ xin,
    float* __restrict__ xout)
{
    int tid = blockIdx.x * blockDim.x + threadIdx.x;
    int node = tid >> 3, sl = tid & 7;
    if (node >= N_NODES) return;
    int d = deg[node];
    if (d > CAP) d = CAP;
    const int* pl = payload + node * CAP;

    float4 a0 = make_float4(0.f,0.f,0.f,0.f), a1 = a0;
    int rounds = (d + 7) >> 3;
    for (int r = 0; r < rounds; ++r) {
        int k = r * 8;
        int4 cA = *(const int4*)(pl + k);
        int4 cB = *(const int4*)(pl + k + 4);
        // clamp garbage indices beyond d to 0 (safe row), mask the add
        int i0 = (k + 0 < d) ? cA.x : 0;  float m0 = (k + 0 < d) ? 1.f : 0.f;
        int i1 = (k + 1 < d) ? cA.y : 0;  float m1 = (k + 1 < d) ? 1.f : 0.f;
        int i2 = (k + 2 < d) ? cA.z : 0;  float m2 = (k + 2 < d) ? 1.f : 0.f;
        int i3 = (k + 3 < d) ? cA.w : 0;  float m3 = (k + 3 < d) ? 1.f : 0.f;
        int i4 = (k + 4 < d) ? cB.x : 0;  float m4 = (k + 4 < d) ? 1.f : 0.f;
        int i5 = (k + 5 < d) ? cB.y : 0;  float m5 = (k + 5 < d) ? 1.f : 0.f;
        int i6 = (k + 6 < d) ? cB.z : 0;  float m6 = (k + 6 < d) ? 1.f : 0.f;
        int i7 = (k + 7 < d) ? cB.w : 0;  float m7 = (k + 7 < d) ? 1.f : 0.f;
        float4 v0 = *(const float4*)(Y + (size_t)i0 * HD + sl * 4);
        float4 v1 = *(const float4*)(Y + (size_t)i1 * HD + sl * 4);
        float4 v2 = *(const float4*)(Y + (size_t)i2 * HD + sl * 4);
        float4 v3 = *(const float4*)(Y + (size_t)i3 * HD + sl * 4);
        float4 v4 = *(const float4*)(Y + (size_t)i4 * HD + sl * 4);
        float4 v5 = *(const float4*)(Y + (size_t)i5 * HD + sl * 4);
        float4 v6 = *(const float4*)(Y + (size_t)i6 * HD + sl * 4);
        float4 v7 = *(const float4*)(Y + (size_t)i7 * HD + sl * 4);
        fmam4(a0, v0, m0); fmam4(a1, v1, m1);
        fmam4(a0, v2, m2); fmam4(a1, v3, m3);
        fmam4(a0, v4, m4); fmam4(a1, v5, m5);
        fmam4(a0, v6, m6); fmam4(a1, v7, m7);
    }
    add4(a0, a1);

    const size_t off = (size_t)node * HD + sl * 4;
    float4 x = *(const float4*)(xin + off);
    x.x = (x.x + a0.x) * 0.5f;
    x.y = (x.y + a0.y) * 0.5f;
    x.z = (x.z + a0.z) * 0.5f;
    x.w = (x.w + a0.w) * 0.5f;
    *(float4*)(xout + off) = x;
}

// Layer-3 gather fused with: L2-normalize ; MLP 32->64 tanh ->64 tanh ->1 ; sigmoid.
// Same 8-lane/node decomposition; natural register allocation (R9: forcing
// waves/EU caused a 366 MB spill; R8 natural = 148 VGPR, no spill).
__global__ __launch_bounds__(256) void k_gather_final(
    const int* __restrict__ deg, const int* __restrict__ payload,
    const float* __restrict__ Y, const float* __restrict__ xin,
    const float* __restrict__ w1, const float* __restrict__ b1,
    const float* __restrict__ w2, const float* __restrict__ b2,
    const float* __restrict__ w3, const float* __restrict__ b3,
    float* __restrict__ out)
{
    int tid = blockIdx.x * blockDim.x + threadIdx.x;
    int node = tid >> 3, q = tid & 7;
    if (node >= N_NODES) return;                 // whole 8-lane group exits together
    int d = deg[node];
    if (d > CAP) d = CAP;
    const int* pl = payload + node * CAP;

    float4 a0 = make_float4(0.f,0.f,0.f,0.f), a1 = a0;
    int rounds = (d + 7) >> 3;
    for (int r = 0; r < rounds; ++r) {
        int k = r * 8;
        int4 cA = *(const int4*)(pl + k);
        int4 cB = *(const int4*)(pl + k + 4);
        int i0 = (k + 0 < d) ? cA.x : 0;  float m0 = (k + 0 < d) ? 1.f : 0.f;
        int i1 = (k + 1 < d) ? cA.y : 0;  float m1 = (k + 1 < d) ? 1.f : 0.f;
        int i2 = (k + 2 < d) ? cA.z : 0;  float m2 = (k + 2 < d) ? 1.f : 0.f;
        int i3 = (k + 3 < d) ? cA.w : 0;  float m3 = (k + 3 < d) ? 1.f : 0.f;
        int i4 = (k + 4 < d) ? cB.x : 0;  float m4 = (k + 4 < d) ? 1.f : 0.f;
        int i5 = (k + 5 < d) ? cB.y : 0;  float m5 = (k + 5 < d) ? 1.f : 0.f;
        int i6 = (k + 6 < d) ? cB.z : 0;  float m6 = (k + 6 < d) ? 1.f : 0.f;
        int i7 = (k + 7 < d) ? cB.w : 0;  float m7 = (k + 7 < d) ? 1.f : 0.f;
        float4 v0 = *(const float4*)(Y + (size_t)i0 * HD + q * 4);
        float4 v1 = *(const float4*)(Y + (size_t)i1 * HD + q * 4);
        float4 v2 = *(const float4*)(Y + (size_t)i2 * HD + q * 4);
        float4 v3 = *(const float4*)(Y + (size_t)i3 * HD + q * 4);
        float4 v4 = *(const float4*)(Y + (size_t)i4 * HD + q * 4);
        float4 v5 = *(const float4*)(Y + (size_t)i5 * HD + q * 4);
        float4 v6 = *(const float4*)(Y + (size_t)i6 * HD + q * 4);
        float4 v7 = *(const float4*)(Y + (size_t)i7 * HD + q * 4);
        fmam4(a0, v0, m0); fmam4(a1, v1, m1);
        fmam4(a0, v2, m2); fmam4(a1, v3, m3);
        fmam4(a0, v4, m4); fmam4(a1, v5, m5);
        fmam4(a0, v6, m6); fmam4(a1, v7, m7);
    }
    add4(a0, a1);

    float4 xo = *(const float4*)(xin + (size_t)node * HD + q * 4);
    xo.x = (xo.x + a0.x) * 0.5f;
    xo.y = (xo.y + a0.y) * 0.5f;
    xo.z = (xo.z + a0.z) * 0.5f;
    xo.w = (xo.w + a0.w) * 0.5f;

    // L2 norm across the 8 lanes
    float ss = xo.x * xo.x + xo.y * xo.y + xo.z * xo.z + xo.w * xo.w;
    ss += __shfl_xor(ss, 1, 8);
    ss += __shfl_xor(ss, 2, 8);
    ss += __shfl_xor(ss, 4, 8);
    float rn = 1.0f / fmaxf(sqrtf(ss), 1e-12f);
    xo.x *= rn; xo.y *= rn; xo.z *= rn; xo.w *= rn;

    // layer 1: h = x @ w1 + b1, cols [8q, 8q+8)
    float4 h0 = *(const float4*)(b1 + q * 8);
    float4 h1 = *(const float4*)(b1 + q * 8 + 4);
    for (int s = 0; s < 8; ++s) {                // rolled: bounded live set
        float m0 = __shfl(xo.x, s, 8);
        float m1 = __shfl(xo.y, s, 8);
        float m2 = __shfl(xo.z, s, 8);
        float m3 = __shfl(xo.w, s, 8);
        const float* wr = w1 + (s * 4) * 64 + q * 8;
        fma4(h0, m0, *(const float4*)(wr));
        fma4(h1, m0, *(const float4*)(wr + 4));
        fma4(h0, m1, *(const float4*)(wr + 64));
        fma4(h1, m1, *(const float4*)(wr + 68));
        fma4(h0, m2, *(const float4*)(wr + 128));
        fma4(h1, m2, *(const float4*)(wr + 132));
        fma4(h0, m3, *(const float4*)(wr + 192));
        fma4(h1, m3, *(const float4*)(wr + 196));
    }
    float t1[8];
    t1[0] = tanhf(h0.x); t1[1] = tanhf(h0.y); t1[2] = tanhf(h0.z); t1[3] = tanhf(h0.w);
    t1[4] = tanhf(h1.x); t1[5] = tanhf(h1.y); t1[6] = tanhf(h1.z); t1[7] = tanhf(h1.w);

    // layer 2: h2 = t1 @ w2 + b2, cols [8q, 8q+8)
    float4 g0 = *(const float4*)(b2 + q * 8);
    float4 g1 = *(const float4*)(b2 + q * 8 + 4);
    for (int s = 0; s < 8; ++s) {                // rolled over source lane
        const float* wr = w2 + (s * 8) * 64 + q * 8;
        #pragma unroll
        for (int c = 0; c < 8; ++c) {
            float m = __shfl(t1[c], s, 8);
            fma4(g0, m, *(const float4*)(wr + c * 64));
            fma4(g1, m, *(const float4*)(wr + c * 64 + 4));
        }
    }

    // layer 3: partial dot over own 8 cols, reduce across the 8 lanes
    float4 wa = *(const float4*)(w3 + q * 8);
    float4 wb = *(const float4*)(w3 + q * 8 + 4);
    float p = 0.f;
    p = fmaf(tanhf(g0.x), wa.x, p);
    p = fmaf(tanhf(g0.y), wa.y, p);
    p = fmaf(tanhf(g0.z), wa.z, p);
    p = fmaf(tanhf(g0.w), wa.w, p);
    p = fmaf(tanhf(g1.x), wb.x, p);
    p = fmaf(tanhf(g1.y), wb.y, p);
    p = fmaf(tanhf(g1.z), wb.z, p);
    p = fmaf(tanhf(g1.w), wb.w, p);
    p += __shfl_xor(p, 1, 8);
    p += __shfl_xor(p, 2, 8);
    p += __shfl_xor(p, 4, 8);
    if (q == 0) out[node] = 1.0f / (1.0f + expf(-(p + b3[0])));
}

extern "C" void kernel_launch(void* const* d_in, const int* in_sizes, int n_in,
                              void* d_out, int out_size, void* d_ws, size_t ws_size,
                              hipStream_t stream) {
    const float* feature = (const float*)d_in[0];
    const float* param   = (const float*)d_in[1];
    const float* w1      = (const float*)d_in[2];
    const float* b1      = (const float*)d_in[3];
    const float* w2      = (const float*)d_in[4];
    const float* b2      = (const float*)d_in[5];
    const float* w3      = (const float*)d_in[6];
    const float* b3      = (const float*)d_in[7];
    const int*   src     = (const int*)d_in[8];
    const int*   dst     = (const int*)d_in[9];
    const int*   pid     = (const int*)d_in[10];
    float* out = (float*)d_out;

    const size_t Y_BYTES   = (size_t)N_ET * N_NODES * HD * sizeof(float);   // 51.2 MB
    const size_t NH_BYTES  = (size_t)N_NODES * HD * sizeof(float);          // 6.4 MB
    const size_t DEG_BYTES = (size_t)N_NODES * sizeof(int);                 // 0.2 MB
    char* p = (char*)d_ws;
    float* Y       = (float*)p;            p += Y_BYTES;
    float* cur     = (float*)p;            p += NH_BYTES;
    int*   deg     = (int*)p;              p += DEG_BYTES;
    int*   payload = (int*)p;              // 50K * 64 * 4B = 12.8 MB

    const int TB = 256;
    const int gT = (N_NODES + TB - 1) / TB;          // 196
    const int gE = (N_EDGES + TB - 1) / TB;
    const int gG = (N_NODES * 8 + TB - 1) / TB;      // 1563
    dim3 gridT(gT, N_ET);                            // 1568 blocks, t uniform per block

    // Build dst-keyed ELL adjacency (int atomics only, once per launch)
    hipMemsetAsync(deg, 0, DEG_BYTES, stream);
    k_count<<<gE, TB, 0, stream>>>(src, dst, pid, deg, payload);

    // layer 1
    k_transform<<<gridT, TB, 0, stream>>>(feature, param, Y);
    k_gather<<<gG, TB, 0, stream>>>(deg, payload, Y, feature, cur);
    // layer 2
    k_transform<<<gridT, TB, 0, stream>>>(cur, param, Y);
    k_gather<<<gG, TB, 0, stream>>>(deg, payload, Y, cur, cur);
    // layer 3: gather fused with normalize + MLP + sigmoid
    k_transform<<<gridT, TB, 0, stream>>>(cur, param, Y);
    k_gather_final<<<gG, TB, 0, stream>>>(deg, payload, Y, cur,
                                          w1, b1, w2, b2, w3, b3, out);
}

// Round 12
// 270.738 us; speedup vs baseline: 1.6799x; 1.0247x over previous
//
#include <hip/hip_runtime.h>
#include <math.h>

#define N_NODES 50000
#define N_EDGES 400000
#define HD 32
#define N_ET 8
#define CAP 64   // ELL capacity; Poisson(8) max degree ~30, P(>=64) ~ 1e-40

__device__ inline void fma4(float4& a, float s, const float4 w) {
    a.x = fmaf(s, w.x, a.x);
    a.y = fmaf(s, w.y, a.y);
    a.z = fmaf(s, w.z, a.z);
    a.w = fmaf(s, w.w, a.w);
}
__device__ inline void add4(float4& a, const float4 v) {
    a.x += v.x; a.y += v.y; a.z += v.z; a.w += v.w;
}

// Build ELL adjacency keyed by dst: payload[d][k] = pid*N_NODES + src
__global__ __launch_bounds__(256) void k_count(
    const int* __restrict__ src, const int* __restrict__ dst,
    const int* __restrict__ pid, int* __restrict__ deg,
    int* __restrict__ payload)
{
    int e = blockIdx.x * blockDim.x + threadIdx.x;
    if (e >= N_EDGES) return;
    int d = dst[e];
    int pos = atomicAdd(&deg[d], 1);
    if (pos < CAP) payload[d * CAP + pos] = pid[e] * N_NODES + src[e];
}

// Transform: Y[t][n] = x[n] @ W_t.  One edge-type per block (blockIdx.y).
// W_t staged in LDS (4 KB); uniform-address ds_read broadcast.
__global__ __launch_bounds__(256) void k_transform(
    const float* __restrict__ xin, const float* __restrict__ param,
    float* __restrict__ Y)
{
    __shared__ float Ws[HD * HD];                 // 4 KB
    const int t = blockIdx.y;
    ((float4*)Ws)[threadIdx.x] =
        ((const float4*)(param + t * HD * HD))[threadIdx.x];
    __syncthreads();

    int n = blockIdx.x * blockDim.x + threadIdx.x;
    if (n >= N_NODES) return;
    const size_t base = (size_t)n * HD;

    float x[HD];
    #pragma unroll
    for (int q = 0; q < 8; ++q) {
        float4 v = *(const float4*)(xin + base + q * 4);
        x[q * 4 + 0] = v.x; x[q * 4 + 1] = v.y;
        x[q * 4 + 2] = v.z; x[q * 4 + 3] = v.w;
    }

    float4 acc[8];
    #pragma unroll
    for (int q = 0; q < 8; ++q) acc[q] = make_float4(0.f, 0.f, 0.f, 0.f);
    #pragma unroll
    for (int i = 0; i < HD; ++i) {
        float xi = x[i];
        #pragma unroll
        for (int q = 0; q < 8; ++q)
            fma4(acc[q], xi, *(const float4*)(Ws + i * HD + q * 4));
    }
    float* yo = Y + (size_t)t * N_NODES * HD + base;
    #pragma unroll
    for (int q = 0; q < 8; ++q) *(float4*)(yo + q * 4) = acc[q];
}

// Gather + combine, 16 lanes/node: lane q owns float2 slice [2q, 2q+2).
// 8 edges in flight per round; tail via clamped-index predication.
__global__ __launch_bounds__(256) void k_gather16(
    const int* __restrict__ deg, const int* __restrict__ payload,
    const float* __restrict__ Y, const float* __restrict__ xin,
    float* __restrict__ xout)
{
    int tid = blockIdx.x * blockDim.x + threadIdx.x;
    int node = tid >> 4, q = tid & 15;
    if (node >= N_NODES) return;
    int d = deg[node];
    if (d > CAP) d = CAP;
    const int* pl = payload + node * CAP;

    float2 a0 = make_float2(0.f, 0.f), a1 = a0;
    int rounds = (d + 7) >> 3;
    for (int r = 0; r < rounds; ++r) {
        int k = r * 8;
        int4 cA = *(const int4*)(pl + k);
        int4 cB = *(const int4*)(pl + k + 4);
        int i0 = (k + 0 < d) ? cA.x : 0;  float m0 = (k + 0 < d) ? 1.f : 0.f;
        int i1 = (k + 1 < d) ? cA.y : 0;  float m1 = (k + 1 < d) ? 1.f : 0.f;
        int i2 = (k + 2 < d) ? cA.z : 0;  float m2 = (k + 2 < d) ? 1.f : 0.f;
        int i3 = (k + 3 < d) ? cA.w : 0;  float m3 = (k + 3 < d) ? 1.f : 0.f;
        int i4 = (k + 4 < d) ? cB.x : 0;  float m4 = (k + 4 < d) ? 1.f : 0.f;
        int i5 = (k + 5 < d) ? cB.y : 0;  float m5 = (k + 5 < d) ? 1.f : 0.f;
        int i6 = (k + 6 < d) ? cB.z : 0;  float m6 = (k + 6 < d) ? 1.f : 0.f;
        int i7 = (k + 7 < d) ? cB.w : 0;  float m7 = (k + 7 < d) ? 1.f : 0.f;
        float2 v0 = *(const float2*)(Y + (size_t)i0 * HD + q * 2);
        float2 v1 = *(const float2*)(Y + (size_t)i1 * HD + q * 2);
        float2 v2 = *(const float2*)(Y + (size_t)i2 * HD + q * 2);
        float2 v3 = *(const float2*)(Y + (size_t)i3 * HD + q * 2);
        float2 v4 = *(const float2*)(Y + (size_t)i4 * HD + q * 2);
        float2 v5 = *(const float2*)(Y + (size_t)i5 * HD + q * 2);
        float2 v6 = *(const float2*)(Y + (size_t)i6 * HD + q * 2);
        float2 v7 = *(const float2*)(Y + (size_t)i7 * HD + q * 2);
        a0.x = fmaf(m0, v0.x, a0.x); a0.y = fmaf(m0, v0.y, a0.y);
        a1.x = fmaf(m1, v1.x, a1.x); a1.y = fmaf(m1, v1.y, a1.y);
        a0.x = fmaf(m2, v2.x, a0.x); a0.y = fmaf(m2, v2.y, a0.y);
        a1.x = fmaf(m3, v3.x, a1.x); a1.y = fmaf(m3, v3.y, a1.y);
        a0.x = fmaf(m4, v4.x, a0.x); a0.y = fmaf(m4, v4.y, a0.y);
        a1.x = fmaf(m5, v5.x, a1.x); a1.y = fmaf(m5, v5.y, a1.y);
        a0.x = fmaf(m6, v6.x, a0.x); a0.y = fmaf(m6, v6.y, a0.y);
        a1.x = fmaf(m7, v7.x, a1.x); a1.y = fmaf(m7, v7.y, a1.y);
    }
    a0.x += a1.x; a0.y += a1.y;

    const size_t off = (size_t)node * HD + q * 2;
    float2 x = *(const float2*)(xin + off);
    x.x = (x.x + a0.x) * 0.5f;
    x.y = (x.y + a0.y) * 0.5f;
    *(float2*)(xout + off) = x;
}

// Layer-3 gather fused with normalize + MLP + sigmoid, 16 lanes/node.
// Lane q owns: input float2 [2q,2q+2), hidden cols [4q,4q+4) both layers.
// Halved per-lane state vs R8's 8-lane version (148 VGPR -> target <~96)
// to escape the 2-waves/SIMD latency trap. Natural register allocation.
__global__ __launch_bounds__(256) void k_gather_final16(
    const int* __restrict__ deg, const int* __restrict__ payload,
    const float* __restrict__ Y, const float* __restrict__ xin,
    const float* __restrict__ w1, const float* __restrict__ b1,
    const float* __restrict__ w2, const float* __restrict__ b2,
    const float* __restrict__ w3, const float* __restrict__ b3,
    float* __restrict__ out)
{
    int tid = blockIdx.x * blockDim.x + threadIdx.x;
    int node = tid >> 4, q = tid & 15;
    if (node >= N_NODES) return;
    int d = deg[node];
    if (d > CAP) d = CAP;
    const int* pl = payload + node * CAP;

    float2 a0 = make_float2(0.f, 0.f), a1 = a0;
    int rounds = (d + 7) >> 3;
    for (int r = 0; r < rounds; ++r) {
        int k = r * 8;
        int4 cA = *(const int4*)(pl + k);
        int4 cB = *(const int4*)(pl + k + 4);
        int i0 = (k + 0 < d) ? cA.x : 0;  float m0 = (k + 0 < d) ? 1.f : 0.f;
        int i1 = (k + 1 < d) ? cA.y : 0;  float m1 = (k + 1 < d) ? 1.f : 0.f;
        int i2 = (k + 2 < d) ? cA.z : 0;  float m2 = (k + 2 < d) ? 1.f : 0.f;
        int i3 = (k + 3 < d) ? cA.w : 0;  float m3 = (k + 3 < d) ? 1.f : 0.f;
        int i4 = (k + 4 < d) ? cB.x : 0;  float m4 = (k + 4 < d) ? 1.f : 0.f;
        int i5 = (k + 5 < d) ? cB.y : 0;  float m5 = (k + 5 < d) ? 1.f : 0.f;
        int i6 = (k + 6 < d) ? cB.z : 0;  float m6 = (k + 6 < d) ? 1.f : 0.f;
        int i7 = (k + 7 < d) ? cB.w : 0;  float m7 = (k + 7 < d) ? 1.f : 0.f;
        float2 v0 = *(const float2*)(Y + (size_t)i0 * HD + q * 2);
        float2 v1 = *(const float2*)(Y + (size_t)i1 * HD + q * 2);
        float2 v2 = *(const float2*)(Y + (size_t)i2 * HD + q * 2);
        float2 v3 = *(const float2*)(Y + (size_t)i3 * HD + q * 2);
        float2 v4 = *(const float2*)(Y + (size_t)i4 * HD + q * 2);
        float2 v5 = *(const float2*)(Y + (size_t)i5 * HD + q * 2);
        float2 v6 = *(const float2*)(Y + (size_t)i6 * HD + q * 2);
        float2 v7 = *(const float2*)(Y + (size_t)i7 * HD + q * 2);
        a0.x = fmaf(m0, v0.x, a0.x); a0.y = fmaf(m0, v0.y, a0.y);
        a1.x = fmaf(m1, v1.x, a1.x); a1.y = fmaf(m1, v1.y, a1.y);
        a0.x = fmaf(m2, v2.x, a0.x); a0.y = fmaf(m2, v2.y, a0.y);
        a1.x = fmaf(m3, v3.x, a1.x); a1.y = fmaf(m3, v3.y, a1.y);
        a0.x = fmaf(m4, v4.x, a0.x); a0.y = fmaf(m4, v4.y, a0.y);
        a1.x = fmaf(m5, v5.x, a1.x); a1.y = fmaf(m5, v5.y, a1.y);
        a0.x = fmaf(m6, v6.x, a0.x); a0.y = fmaf(m6, v6.y, a0.y);
        a1.x = fmaf(m7, v7.x, a1.x); a1.y = fmaf(m7, v7.y, a1.y);
    }
    a0.x += a1.x; a0.y += a1.y;

    float2 xo = *(const float2*)(xin + (size_t)node * HD + q * 2);
    xo.x = (xo.x + a0.x) * 0.5f;
    xo.y = (xo.y + a0.y) * 0.5f;

    // L2 norm across the 16 lanes
    float ss = xo.x * xo.x + xo.y * xo.y;
    ss += __shfl_xor(ss, 1, 16);
    ss += __shfl_xor(ss, 2, 16);
    ss += __shfl_xor(ss, 4, 16);
    ss += __shfl_xor(ss, 8, 16);
    float rn = 1.0f / fmaxf(sqrtf(ss), 1e-12f);
    xo.x *= rn; xo.y *= rn;

    // layer 1: h = x @ w1 + b1, cols [4q, 4q+4)
    float4 h = *(const float4*)(b1 + q * 4);
    for (int s = 0; s < 16; ++s) {               // rolled: bounded live set
        float m0 = __shfl(xo.x, s, 16);          // x[2s]
        float m1 = __shfl(xo.y, s, 16);          // x[2s+1]
        const float* wr = w1 + (2 * s) * 64 + q * 4;
        fma4(h, m0, *(const float4*)(wr));
        fma4(h, m1, *(const float4*)(wr + 64));
    }
    float t1[4];
    t1[0] = tanhf(h.x); t1[1] = tanhf(h.y);
    t1[2] = tanhf(h.z); t1[3] = tanhf(h.w);

    // layer 2: g = t1 @ w2 + b2, cols [4q, 4q+4)
    float4 g = *(const float4*)(b2 + q * 4);
    for (int s = 0; s < 16; ++s) {               // rolled over source lane
        const float* wr = w2 + (4 * s) * 64 + q * 4;
        #pragma unroll
        for (int c = 0; c < 4; ++c) {
            float m = __shfl(t1[c], s, 16);      // hidden[4s+c]
            fma4(g, m, *(const float4*)(wr + c * 64));
        }
    }

    // layer 3: partial dot over own 4 cols, reduce across the 16 lanes
    float4 wa = *(const float4*)(w3 + q * 4);
    float p = 0.f;
    p = fmaf(tanhf(g.x), wa.x, p);
    p = fmaf(tanhf(g.y), wa.y, p);
    p = fmaf(tanhf(g.z), wa.z, p);
    p = fmaf(tanhf(g.w), wa.w, p);
    p += __shfl_xor(p, 1, 16);
    p += __shfl_xor(p, 2, 16);
    p += __shfl_xor(p, 4, 16);
    p += __shfl_xor(p, 8, 16);
    if (q == 0) out[node] = 1.0f / (1.0f + expf(-(p + b3[0])));
}

extern "C" void kernel_launch(void* const* d_in, const int* in_sizes, int n_in,
                              void* d_out, int out_size, void* d_ws, size_t ws_size,
                              hipStream_t stream) {
    const float* feature = (const float*)d_in[0];
    const float* param   = (const float*)d_in[1];
    const float* w1      = (const float*)d_in[2];
    const float* b1      = (const float*)d_in[3];
    const float* w2      = (const float*)d_in[4];
    const float* b2      = (const float*)d_in[5];
    const float* w3      = (const float*)d_in[6];
    const float* b3      = (const float*)d_in[7];
    const int*   src     = (const int*)d_in[8];
    const int*   dst     = (const int*)d_in[9];
    const int*   pid     = (const int*)d_in[10];
    float* out = (float*)d_out;

    const size_t Y_BYTES   = (size_t)N_ET * N_NODES * HD * sizeof(float);   // 51.2 MB
    const size_t NH_BYTES  = (size_t)N_NODES * HD * sizeof(float);          // 6.4 MB
    const size_t DEG_BYTES = (size_t)N_NODES * sizeof(int);                 // 0.2 MB
    char* p = (char*)d_ws;
    float* Y       = (float*)p;            p += Y_BYTES;
    float* cur     = (float*)p;            p += NH_BYTES;
    int*   deg     = (int*)p;              p += DEG_BYTES;
    int*   payload = (int*)p;              // 50K * 64 * 4B = 12.8 MB

    const int TB = 256;
    const int gT = (N_NODES + TB - 1) / TB;            // 196
    const int gE = (N_EDGES + TB - 1) / TB;
    const int gG = (N_NODES * 16 + TB - 1) / TB;       // 3125 (exact)
    dim3 gridT(gT, N_ET);                              // 1568 blocks, t uniform per block

    // Build dst-keyed ELL adjacency (int atomics only, once per launch)
    hipMemsetAsync(deg, 0, DEG_BYTES, stream);
    k_count<<<gE, TB, 0, stream>>>(src, dst, pid, deg, payload);

    // layer 1
    k_transform<<<gridT, TB, 0, stream>>>(feature, param, Y);
    k_gather16<<<gG, TB, 0, stream>>>(deg, payload, Y, feature, cur);
    // layer 2
    k_transform<<<gridT, TB, 0, stream>>>(cur, param, Y);
    k_gather16<<<gG, TB, 0, stream>>>(deg, payload, Y, cur, cur);
    // layer 3: gather fused with normalize + MLP + sigmoid
    k_transform<<<gridT, TB, 0, stream>>>(cur, param, Y);
    k_gather_final16<<<gG, TB, 0, stream>>>(deg, payload, Y, cur,
                                            w1, b1, w2, b2, w3, b3, out);
}